// Round 2
// baseline (449.243 us; speedup 1.0000x reference)
//
#include <hip/hip_runtime.h>

#define NG 12
#define SD 64
#define ED 768
#define NB 262144
#define ROWS 128        // rows per block (contiguous)
#define TPB 192         // 3 waves; thread t owns output cols [4t, 4t+4)

// M[g][o] = sum_s Wg[g][s] * Wagg[o][g*64+s];  Mb[g][o] = same with bg
__global__ void fge_pre1(const float* __restrict__ Wg,
                         const float* __restrict__ bg,
                         const float* __restrict__ Wagg,
                         float* __restrict__ M, float* __restrict__ Mb)
{
    int tid = blockIdx.x * blockDim.x + threadIdx.x;
    if (tid >= ED * NG) return;
    int o = tid / NG, g = tid % NG;   // 12 consecutive threads share one Wagg row
    const float* wrow = Wagg + (size_t)o * ED + g * SD;
    const float* wgp  = Wg + g * SD;
    const float* bgp  = bg + g * SD;
    float m = 0.f, mb = 0.f;
    #pragma unroll
    for (int s = 0; s < SD; ++s) {
        float w = wrow[s];
        m  += wgp[s] * w;
        mb += bgp[s] * w;
    }
    M [g * ED + o] = m;
    Mb[g * ED + o] = mb;
}

// c0[o] = bagg[o] + sum_g Mb[g][o]
__global__ void fge_pre2(const float* __restrict__ Mb,
                         const float* __restrict__ bagg,
                         float* __restrict__ c0)
{
    int o = blockIdx.x * blockDim.x + threadIdx.x;
    if (o >= ED) return;
    float s = bagg[o];
    #pragma unroll
    for (int g = 0; g < NG; ++g) s += Mb[g * ED + o];
    c0[o] = s;
}

// out[b][o] = c0[o] + sum_g counts[b][g] * M[g][o]
__global__ __launch_bounds__(TPB, 4) void fge_main(const int* __restrict__ counts,
                                                   const float* __restrict__ M,
                                                   const float* __restrict__ c0,
                                                   float* __restrict__ out)
{
    __shared__ float scf[ROWS * NG];   // 6 KB: this block's counts, pre-converted
    const int t = threadIdx.x;
    const size_t b0 = (size_t)blockIdx.x * ROWS;

    // Stage + convert counts once: 1536 ints = 384 int4, 192 threads x 2
    {
        const int4* src = reinterpret_cast<const int4*>(counts + b0 * NG);
        float4* dst = reinterpret_cast<float4*>(scf);
        int4 a = src[t], b = src[t + TPB];
        dst[t]       = make_float4((float)a.x, (float)a.y, (float)a.z, (float)a.w);
        dst[t + TPB] = make_float4((float)b.x, (float)b.y, (float)b.z, (float)b.w);
    }

    // Per-thread column slice of M and c0 in registers (reused for all 128 rows)
    float m[NG][4];
    #pragma unroll
    for (int g = 0; g < NG; ++g) {
        float4 v = *reinterpret_cast<const float4*>(M + g * ED + t * 4);
        m[g][0] = v.x; m[g][1] = v.y; m[g][2] = v.z; m[g][3] = v.w;
    }
    const float4 base = *reinterpret_cast<const float4*>(c0 + t * 4);
    __syncthreads();

    float* orow = out + b0 * ED + t * 4;
    #pragma unroll 2
    for (int r = 0; r < ROWS; ++r) {
        // uniform-address LDS reads -> broadcast, conflict-free
        const float4* cf4 = reinterpret_cast<const float4*>(scf + r * NG);
        float4 ca = cf4[0], cb = cf4[1], cc = cf4[2];
        float cf[NG] = { ca.x, ca.y, ca.z, ca.w,
                         cb.x, cb.y, cb.z, cb.w,
                         cc.x, cc.y, cc.z, cc.w };
        float4 acc = base;
        #pragma unroll
        for (int g = 0; g < NG; ++g) {
            acc.x = fmaf(cf[g], m[g][0], acc.x);
            acc.y = fmaf(cf[g], m[g][1], acc.y);
            acc.z = fmaf(cf[g], m[g][2], acc.z);
            acc.w = fmaf(cf[g], m[g][3], acc.w);
        }
        *reinterpret_cast<float4*>(orow + (size_t)r * ED) = acc;
    }
}

extern "C" void kernel_launch(void* const* d_in, const int* in_sizes, int n_in,
                              void* d_out, int out_size, void* d_ws, size_t ws_size,
                              hipStream_t stream) {
    const int*   counts = (const int*)  d_in[0];
    const float* Wg     = (const float*)d_in[1];
    const float* bg     = (const float*)d_in[2];
    const float* Wagg   = (const float*)d_in[3];
    const float* bagg   = (const float*)d_in[4];
    float* out = (float*)d_out;

    float* M  = (float*)d_ws;            // 12*768 = 36 KB
    float* Mb = M  + NG * ED;            // 36 KB
    float* c0 = Mb + NG * ED;            // 3 KB

    fge_pre1<<<(ED * NG + 255) / 256, 256, 0, stream>>>(Wg, bg, Wagg, M, Mb);
    fge_pre2<<<(ED + 255) / 256, 256, 0, stream>>>(Mb, bagg, c0);
    fge_main<<<NB / ROWS, TPB, 0, stream>>>(counts, M, c0, out);
}

// Round 3
// 232.493 us; speedup vs baseline: 1.9323x; 1.9323x over previous
//
#include <hip/hip_runtime.h>

#define NG 12
#define SD 64
#define ED 768
#define NB 262144
#define TPB 192          // 3 waves; thread t owns output cols [4t, 4t+4)
#define G   2048         // grid size; 128 grid-stride iterations per block

// M[g][o] = sum_s Wg[g][s] * Wagg[o][g*64+s];  Mb[g][o] = same with bg
__global__ void fge_pre1(const float* __restrict__ Wg,
                         const float* __restrict__ bg,
                         const float* __restrict__ Wagg,
                         float* __restrict__ M, float* __restrict__ Mb)
{
    int tid = blockIdx.x * blockDim.x + threadIdx.x;
    if (tid >= ED * NG) return;
    int o = tid / NG, g = tid % NG;   // 12 consecutive threads share one Wagg row
    const float* wrow = Wagg + (size_t)o * ED + g * SD;
    const float* wgp  = Wg + g * SD;
    const float* bgp  = bg + g * SD;
    float m = 0.f, mb = 0.f;
    #pragma unroll
    for (int s = 0; s < SD; ++s) {
        float w = wrow[s];
        m  += wgp[s] * w;
        mb += bgp[s] * w;
    }
    M [g * ED + o] = m;
    Mb[g * ED + o] = mb;
}

// c0[o] = bagg[o] + sum_g Mb[g][o]
__global__ void fge_pre2(const float* __restrict__ Mb,
                         const float* __restrict__ bagg,
                         float* __restrict__ c0)
{
    int o = blockIdx.x * blockDim.x + threadIdx.x;
    if (o >= ED) return;
    float s = bagg[o];
    #pragma unroll
    for (int g = 0; g < NG; ++g) s += Mb[g * ED + o];
    c0[o] = s;
}

__device__ __forceinline__ void row_compute(int4 x, int4 y, int4 z,
                                            const float (&m)[NG][4],
                                            float4 base, float* __restrict__ dst)
{
    float cf[NG] = { (float)x.x, (float)x.y, (float)x.z, (float)x.w,
                     (float)y.x, (float)y.y, (float)y.z, (float)y.w,
                     (float)z.x, (float)z.y, (float)z.z, (float)z.w };
    float4 acc = base;
    #pragma unroll
    for (int g = 0; g < NG; ++g) {
        acc.x = fmaf(cf[g], m[g][0], acc.x);
        acc.y = fmaf(cf[g], m[g][1], acc.y);
        acc.z = fmaf(cf[g], m[g][2], acc.z);
        acc.w = fmaf(cf[g], m[g][3], acc.w);
    }
    *reinterpret_cast<float4*>(dst) = acc;
}

// out[b][o] = c0[o] + sum_g counts[b][g] * M[g][o]
// Grid-stride (compact moving write window) + 2-deep scalar count prefetch.
__global__ __launch_bounds__(TPB) void fge_main(const int* __restrict__ counts,
                                                const float* __restrict__ M,
                                                const float* __restrict__ c0,
                                                float* __restrict__ out)
{
    const int t  = threadIdx.x;
    const int o0 = t * 4;

    float m[NG][4];
    #pragma unroll
    for (int g = 0; g < NG; ++g) {
        float4 v = *reinterpret_cast<const float4*>(M + g * ED + o0);
        m[g][0] = v.x; m[g][1] = v.y; m[g][2] = v.z; m[g][3] = v.w;
    }
    const float4 base = *reinterpret_cast<const float4*>(c0 + o0);

    const int4* cp = reinterpret_cast<const int4*>(counts);  // 3 int4 per row

    int b = blockIdx.x;
    // prime 2-deep prefetch: rows b and b+G (uniform addr -> s_load_dwordx4)
    int4 A0 = cp[b * 3], A1 = cp[b * 3 + 1], A2 = cp[b * 3 + 2];
    int nb1 = b + G;
    int4 B0 = cp[nb1 * 3], B1 = cp[nb1 * 3 + 1], B2 = cp[nb1 * 3 + 2];

    #pragma unroll 1
    for (int i = 0; i < NB / G; i += 2) {
        row_compute(A0, A1, A2, m, base, out + (size_t)b * ED + o0);
        int pa = b + 2 * G; pa = pa < NB ? pa : NB - 1;      // clamp tail
        A0 = cp[pa * 3]; A1 = cp[pa * 3 + 1]; A2 = cp[pa * 3 + 2];

        row_compute(B0, B1, B2, m, base, out + (size_t)(b + G) * ED + o0);
        int pb = b + 3 * G; pb = pb < NB ? pb : NB - 1;
        B0 = cp[pb * 3]; B1 = cp[pb * 3 + 1]; B2 = cp[pb * 3 + 2];

        b += 2 * G;
    }
}

extern "C" void kernel_launch(void* const* d_in, const int* in_sizes, int n_in,
                              void* d_out, int out_size, void* d_ws, size_t ws_size,
                              hipStream_t stream) {
    const int*   counts = (const int*)  d_in[0];
    const float* Wg     = (const float*)d_in[1];
    const float* bg     = (const float*)d_in[2];
    const float* Wagg   = (const float*)d_in[3];
    const float* bagg   = (const float*)d_in[4];
    float* out = (float*)d_out;

    float* M  = (float*)d_ws;            // 12*768 = 36 KB
    float* Mb = M  + NG * ED;            // 36 KB
    float* c0 = Mb + NG * ED;            // 3 KB

    fge_pre1<<<(ED * NG + 255) / 256, 256, 0, stream>>>(Wg, bg, Wagg, M, Mb);
    fge_pre2<<<(ED + 255) / 256, 256, 0, stream>>>(Mb, bagg, c0);
    fge_main<<<G, TPB, 0, stream>>>(counts, M, c0, out);
}